// Round 1
// baseline (938.682 us; speedup 1.0000x reference)
//
#include <hip/hip_runtime.h>
#include <hip/hip_bf16.h>
#include <stdint.h>

#define N_NODES 50000
#define N_EDGES 800000
#define IN_DIM 64
#define HID 128
#define OUT_DIM 64
#define T_HIST 8

typedef __attribute__((ext_vector_type(8))) short short8;
typedef __attribute__((ext_vector_type(4))) float f32x4;
typedef __attribute__((ext_vector_type(4))) unsigned short us4;

__device__ __forceinline__ unsigned short f2bf(float x) {
  unsigned int u = __builtin_bit_cast(unsigned int, x);
  unsigned int r = (u + 0x7FFFu + ((u >> 16) & 1u)) >> 16;
  return (unsigned short)r;
}
__device__ __forceinline__ float bf2f(unsigned short b) {
  unsigned int u = ((unsigned int)b) << 16;
  return __builtin_bit_cast(float, u);
}
__device__ __forceinline__ float sigm(float x) {
  x = fminf(fmaxf(x, -30.f), 30.f);
  return 1.f / (1.f + __expf(-x));
}
__device__ __forceinline__ float tanh_f(float x) {
  x = fminf(fmaxf(x, -15.f), 15.f);
  float e = __expf(2.f * x);
  return (e - 1.f) / (e + 1.f);
}

// ---------------- prepack: transpose weights to bf16 [c][k] ----------------
__global__ void prepack_kernel(const float* __restrict__ w_ih, const float* __restrict__ w_hh,
                               const float* __restrict__ W_cls,
                               unsigned short* __restrict__ Wt, unsigned short* __restrict__ Wc) {
  int tid = blockIdx.x * blockDim.x + threadIdx.x;
  int stride = gridDim.x * blockDim.x;
  // Wt[c][k], c in [0,512) gate-col, k in [0,256): k<128 -> w_ih[k][c], else w_hh[k-128][c]
  for (int idx = tid; idx < 512 * 256; idx += stride) {
    int k = idx >> 9;       // 0..255
    int c = idx & 511;      // 0..511 (fast -> coalesced reads)
    float v = (k < 128) ? w_ih[k * 512 + c] : w_hh[(k - 128) * 512 + c];
    Wt[c * 256 + k] = f2bf(v);
  }
  // Wc[c][k], c in [0,64), k in [0,128): W_cls[k][c]
  for (int idx = tid; idx < 64 * 128; idx += stride) {
    int k = idx >> 6;
    int c = idx & 63;
    Wc[c * 128 + k] = f2bf(W_cls[k * 64 + c]);
  }
}

// ---------------- degree count ----------------
__global__ void deg_kernel(const int* __restrict__ dst, float* __restrict__ deg) {
  int e = blockIdx.x * blockDim.x + threadIdx.x;
  if (e < N_EDGES) atomicAdd(&deg[dst[e]], 1.0f);
}

// ---------------- edge scatter: msg[dst] += feats[src] ----------------
__global__ void scatter_kernel(const float* __restrict__ feats, const int* __restrict__ src,
                               const int* __restrict__ dst, float* __restrict__ msg) {
  int gtid = blockIdx.x * blockDim.x + threadIdx.x;
  int wave = gtid >> 6;
  int lane = threadIdx.x & 63;
  int nwaves = (gridDim.x * blockDim.x) >> 6;
  for (int e = wave; e < N_EDGES; e += nwaves) {
    int s = src[e];
    int d = dst[e];
    float v = feats[s * 64 + lane];
    atomicAdd(&msg[d * 64 + lane], v);
  }
}

// ---------------- h_struct = nf@W_self + (msg/deg)@W_neigh + b ----------------
#define HS_TILE 32
__global__ __launch_bounds__(256) void hstruct_kernel(
    const float* __restrict__ nf, const float* __restrict__ msg, const float* __restrict__ deg,
    const float* __restrict__ Wself, const float* __restrict__ Wneigh, const float* __restrict__ bs,
    float* __restrict__ hstruct) {
  __shared__ float s_nf[HS_TILE][IN_DIM + 1];
  __shared__ float s_hn[HS_TILE][IN_DIM + 1];
  __shared__ float s_scale[HS_TILE];
  int tid = threadIdx.x;
  int node0 = blockIdx.x * HS_TILE;
  for (int i = tid; i < HS_TILE * IN_DIM; i += 256) {
    int r = i >> 6, k = i & 63;
    int node = node0 + r;
    float a = 0.f, m = 0.f;
    if (node < N_NODES) { a = nf[node * 64 + k]; m = msg[node * 64 + k]; }
    s_nf[r][k] = a;
    s_hn[r][k] = m;
  }
  if (tid < HS_TILE) {
    int node = node0 + tid;
    float d = (node < N_NODES) ? deg[node] : 1.f;
    s_scale[tid] = 1.f / fmaxf(d, 1.f);
  }
  __syncthreads();
  int r = tid & 31;
  int c0 = (tid >> 5) * 16;
  float accs[16], accn[16];
  #pragma unroll
  for (int i = 0; i < 16; i++) { accs[i] = 0.f; accn[i] = 0.f; }
  for (int k = 0; k < IN_DIM; k++) {
    float a = s_nf[r][k];
    float b = s_hn[r][k];
    const float4* ws = (const float4*)&Wself[k * HID + c0];
    const float4* wn = (const float4*)&Wneigh[k * HID + c0];
    #pragma unroll
    for (int q = 0; q < 4; q++) {
      float4 w1 = ws[q]; float4 w2 = wn[q];
      accs[q*4+0] += a * w1.x; accs[q*4+1] += a * w1.y;
      accs[q*4+2] += a * w1.z; accs[q*4+3] += a * w1.w;
      accn[q*4+0] += b * w2.x; accn[q*4+1] += b * w2.y;
      accn[q*4+2] += b * w2.z; accn[q*4+3] += b * w2.w;
    }
  }
  int node = node0 + r;
  if (node < N_NODES) {
    float sc = s_scale[r];
    #pragma unroll
    for (int i = 0; i < 16; i++)
      hstruct[(size_t)node * HID + c0 + i] = accs[i] + sc * accn[i] + bs[c0 + i];
  }
}

// ---------------- fused LSTM (8 steps) + classifier ----------------
// block: 512 threads (8 waves), 64 nodes. Wave w computes gate cols [w*64, w*64+64).
// A = [x_t | h] bf16 in LDS, swizzled. W slices staged per 32-k step.
#define LB 64
__global__ __launch_bounds__(512) void lstm_kernel(
    const float* __restrict__ hist,          // [N][8][128]
    const unsigned short* __restrict__ Wt,   // [512][256] bf16
    const unsigned short* __restrict__ Wc,   // [64][128] bf16
    const float* __restrict__ b_lstm,        // [512]
    const float* __restrict__ hstruct,       // [N][128]
    const float* __restrict__ b_cls,         // [64]
    float* __restrict__ out)                 // [N][64]
{
  __shared__ alignas(16) unsigned short Abuf[64 * 256];  // 32KB [row][sb(kb,row)][8]
  __shared__ alignas(16) unsigned short Wsl[512 * 32];   // 32KB
  __shared__ alignas(16) unsigned short Gat[512 * 64];   // 64KB [col][rblk^..][4]

  const int tid = threadIdx.x;
  const int lane = tid & 63;
  const int w = tid >> 6;
  const int l15 = lane & 15;
  const int l4 = lane >> 4;
  const int base = blockIdx.x * LB;

  // elementwise ownership: thread -> (hidden j, row group)
  const int j = tid >> 2;          // 0..127
  const int rsub = tid & 3;        // 0..3
  const int rbase = rsub * 16;

  float c_st[16], h_reg[16];
  #pragma unroll
  for (int i = 0; i < 16; i++) { c_st[i] = 0.f; h_reg[i] = 0.f; }

  const float bi = b_lstm[j];
  const float bf_ = b_lstm[128 + j];
  const float bg = b_lstm[256 + j];
  const float bo = b_lstm[384 + j];

  // zero h-region of A (kb 16..31 <-> ushort offsets row*256 + [128,256))
  for (int u = tid; u < 64 * 16; u += 512) {
    int row = u >> 4;
    int kbh = u & 15;
    short8 z = {0,0,0,0,0,0,0,0};
    *(short8*)&Abuf[row * 256 + 128 + kbh * 8] = z;
  }

  for (int t = 0; t < T_HIST; t++) {
    // stage x_t into A x-region (bf16, swizzled)
    #pragma unroll
    for (int i = 0; i < 2; i++) {
      int u = tid + i * 512;       // 0..1023
      int row = u >> 4;
      int kb = u & 15;
      int node = base + row;
      float4 x0 = make_float4(0.f,0.f,0.f,0.f), x1 = make_float4(0.f,0.f,0.f,0.f);
      if (node < N_NODES) {
        const float4* p = (const float4*)&hist[((size_t)node * 8 + t) * 128 + kb * 8];
        x0 = p[0]; x1 = p[1];
      }
      short8 v;
      v[0] = (short)f2bf(x0.x); v[1] = (short)f2bf(x0.y);
      v[2] = (short)f2bf(x0.z); v[3] = (short)f2bf(x0.w);
      v[4] = (short)f2bf(x1.x); v[5] = (short)f2bf(x1.y);
      v[6] = (short)f2bf(x1.z); v[7] = (short)f2bf(x1.w);
      int sb = (kb & 8) | ((kb & 7) ^ (row & 7));
      *(short8*)&Abuf[row * 256 + sb * 8] = v;
    }
    __syncthreads();   // A ready (x new, h from t-1)

    f32x4 acc[4][4];
    #pragma unroll
    for (int a = 0; a < 4; a++)
      #pragma unroll
      for (int b = 0; b < 4; b++) {
        f32x4 z = {0.f,0.f,0.f,0.f};
        acc[a][b] = z;
      }

    for (int kk = 0; kk < 8; kk++) {
      // stage W slice (rows kk*32..kk*32+32 of combined [Wih;Whh], transposed)
      #pragma unroll
      for (int i = 0; i < 4; i++) {
        int u = tid + i * 512;     // 0..2047
        int c = u >> 2;
        int kb = u & 3;
        short8 v = *(const short8*)&Wt[c * 256 + kk * 32 + kb * 8];
        *(short8*)&Wsl[c * 32 + ((kb ^ (c & 3)) * 8)] = v;
      }
      __syncthreads();  // W slice ready
      short8 afr[4], bfr[4];
      #pragma unroll
      for (int rb = 0; rb < 4; rb++) {
        int row = rb * 16 + l15;
        int kb = kk * 4 + l4;
        int sb = (kb & 24) | ((kb & 7) ^ (row & 7));
        afr[rb] = *(const short8*)&Abuf[row * 256 + sb * 8];
      }
      #pragma unroll
      for (int cb = 0; cb < 4; cb++) {
        int c = w * 64 + cb * 16 + l15;
        bfr[cb] = *(const short8*)&Wsl[c * 32 + ((l4 ^ (c & 3)) * 8)];
      }
      #pragma unroll
      for (int rb = 0; rb < 4; rb++)
        #pragma unroll
        for (int cb = 0; cb < 4; cb++)
          acc[rb][cb] = __builtin_amdgcn_mfma_f32_16x16x32_bf16(afr[rb], bfr[cb], acc[rb][cb], 0, 0, 0);
      __syncthreads();  // all reads done before next slice overwrite
    }

    // write gates (bf16) to Gat[col][row], swizzled 8B units
    #pragma unroll
    for (int rb = 0; rb < 4; rb++) {
      #pragma unroll
      for (int cb = 0; cb < 4; cb++) {
        int col = w * 64 + cb * 16 + l15;
        int r0 = rb * 16 + l4 * 4;
        us4 pk;
        pk[0] = f2bf(acc[rb][cb][0]);
        pk[1] = f2bf(acc[rb][cb][1]);
        pk[2] = f2bf(acc[rb][cb][2]);
        pk[3] = f2bf(acc[rb][cb][3]);
        int rblk = r0 >> 2;
        *(us4*)&Gat[col * 64 + ((rblk ^ (col & 15)) * 4)] = pk;
      }
    }
    __syncthreads();  // gates visible

    // elementwise LSTM cell update; write h (bf16) into A h-region
    {
      float val[4][16];
      #pragma unroll
      for (int g = 0; g < 4; g++) {
        int col = g * 128 + j;
        #pragma unroll
        for (int q = 0; q < 4; q++) {
          int rblk = rsub * 4 + q;
          us4 pk = *(const us4*)&Gat[col * 64 + ((rblk ^ (col & 15)) * 4)];
          val[g][q*4+0] = bf2f(pk[0]);
          val[g][q*4+1] = bf2f(pk[1]);
          val[g][q*4+2] = bf2f(pk[2]);
          val[g][q*4+3] = bf2f(pk[3]);
        }
      }
      #pragma unroll
      for (int rr = 0; rr < 16; rr++) {
        float si = sigm(val[0][rr] + bi);
        float sf = sigm(val[1][rr] + bf_);
        float tg = tanh_f(val[2][rr] + bg);
        float so = sigm(val[3][rr] + bo);
        float c = sf * c_st[rr] + si * tg;
        c_st[rr] = c;
        float h = so * tanh_f(c);
        h_reg[rr] = h;
        int row = rbase + rr;
        int kb = 16 + (j >> 3);
        int sb = (kb & 24) | ((kb & 7) ^ (row & 7));
        Abuf[row * 256 + sb * 8 + (j & 7)] = f2bf(h);
      }
    }
    // no barrier needed here: next x-stage writes a disjoint region; the
    // barrier after x-stage orders all h-writes before the next A reads.
  }

  // ---------------- epilogue: out = (h_struct + h)@W_cls + b_cls ----------------
  // stage Wc into Wsl (reuse), layout [c][16 kb swz][8]
  #pragma unroll
  for (int i = 0; i < 2; i++) {
    int u = tid + i * 512;   // 0..1023
    int c = u >> 4;
    int kb = u & 15;
    short8 v = *(const short8*)&Wc[c * 128 + kb * 8];
    int sb = (kb & 12) | ((kb & 3) ^ (c & 3));
    *(short8*)&Wsl[c * 128 + sb * 8] = v;
  }
  // combined = h_struct + h -> A x-region (bf16)
  #pragma unroll
  for (int rr = 0; rr < 16; rr++) {
    int row = rbase + rr;
    int node = base + row;
    float hs = (node < N_NODES) ? hstruct[(size_t)node * 128 + j] : 0.f;
    float comb = hs + h_reg[rr];
    int kb = j >> 3;
    int sb = (kb & 8) | ((kb & 7) ^ (row & 7));
    Abuf[row * 256 + sb * 8 + (j & 7)] = f2bf(comb);
  }
  __syncthreads();

  // out tile [64][64] = 16 frags; wave w does frags 2w, 2w+1
  #pragma unroll
  for (int fi = 0; fi < 2; fi++) {
    int f = w * 2 + fi;
    int rb = f >> 2, cb = f & 3;
    f32x4 o = {0.f,0.f,0.f,0.f};
    #pragma unroll
    for (int kk = 0; kk < 4; kk++) {
      int row = rb * 16 + l15;
      int kb = kk * 4 + l4;
      int sb = (kb & 8) | ((kb & 7) ^ (row & 7));
      short8 a = *(const short8*)&Abuf[row * 256 + sb * 8];
      int c = cb * 16 + l15;
      int sbw = (kb & 12) | ((kb & 3) ^ (c & 3));
      short8 bv = *(const short8*)&Wsl[c * 128 + sbw * 8];
      o = __builtin_amdgcn_mfma_f32_16x16x32_bf16(a, bv, o, 0, 0, 0);
    }
    int col = cb * 16 + l15;
    float bcv = b_cls[col];
    #pragma unroll
    for (int reg = 0; reg < 4; reg++) {
      int row = rb * 16 + l4 * 4 + reg;
      int node = base + row;
      if (node < N_NODES) out[(size_t)node * 64 + col] = o[reg] + bcv;
    }
  }
}

// ---------------- launch ----------------
extern "C" void kernel_launch(void* const* d_in, const int* in_sizes, int n_in,
                              void* d_out, int out_size, void* d_ws, size_t ws_size,
                              hipStream_t stream) {
  (void)in_sizes; (void)n_in; (void)out_size; (void)ws_size;
  const float* node_feats = (const float*)d_in[0];
  const float* hist       = (const float*)d_in[1];
  const int*   src        = (const int*)d_in[2];
  const int*   dst        = (const int*)d_in[3];
  const float* W_self     = (const float*)d_in[4];
  const float* W_neigh    = (const float*)d_in[5];
  const float* b_sage     = (const float*)d_in[6];
  const float* w_ih       = (const float*)d_in[7];
  const float* w_hh       = (const float*)d_in[8];
  const float* b_lstm     = (const float*)d_in[9];
  const float* W_cls      = (const float*)d_in[10];
  const float* b_cls      = (const float*)d_in[11];
  float* out = (float*)d_out;

  char* ws = (char*)d_ws;
  float* msg            = (float*)(ws);                 // 50000*64*4 = 12,800,000
  float* deg            = (float*)(ws + 12800000);      // 200,000
  float* hstruct        = (float*)(ws + 13000192);      // 25,600,000
  unsigned short* Wt    = (unsigned short*)(ws + 38600192);  // 262,144
  unsigned short* Wc    = (unsigned short*)(ws + 38862336);  // 16,384

  hipMemsetAsync(msg, 0, 12800000, stream);
  hipMemsetAsync(deg, 0, 200000, stream);
  prepack_kernel<<<64, 256, 0, stream>>>(w_ih, w_hh, W_cls, Wt, Wc);
  deg_kernel<<<(N_EDGES + 255) / 256, 256, 0, stream>>>(dst, deg);
  scatter_kernel<<<2048, 256, 0, stream>>>(node_feats, src, dst, msg);
  hstruct_kernel<<<(N_NODES + HS_TILE - 1) / HS_TILE, 256, 0, stream>>>(
      node_feats, msg, deg, W_self, W_neigh, b_sage, hstruct);
  lstm_kernel<<<(N_NODES + LB - 1) / LB, 512, 0, stream>>>(
      hist, Wt, Wc, b_lstm, hstruct, b_cls, out);
}

// Round 2
// 766.367 us; speedup vs baseline: 1.2248x; 1.2248x over previous
//
#include <hip/hip_runtime.h>
#include <hip/hip_bf16.h>
#include <stdint.h>

#define N_NODES 50000
#define N_EDGES 800000
#define IN_DIM 64
#define HID 128
#define OUT_DIM 64
#define T_HIST 8

#define NB_SCAN ((N_NODES + 1023) / 1024)   // 49

typedef __attribute__((ext_vector_type(8))) short short8;
typedef __attribute__((ext_vector_type(4))) float f32x4;

__device__ __forceinline__ unsigned short f2bf(float x) {
  unsigned int u = __builtin_bit_cast(unsigned int, x);
  unsigned int r = (u + 0x7FFFu + ((u >> 16) & 1u)) >> 16;
  return (unsigned short)r;
}
__device__ __forceinline__ float sigm(float x) {
  x = fminf(fmaxf(x, -30.f), 30.f);
  return 1.f / (1.f + __expf(-x));
}
__device__ __forceinline__ float tanh_f(float x) {
  x = fminf(fmaxf(x, -15.f), 15.f);
  float e = __expf(2.f * x);
  return (e - 1.f) / (e + 1.f);
}

// ---------------- prepack: fragment-ordered bf16 weights ----------------
// Wt2: 256 frags (F = w*32 + g*8 + kk) x 64 lanes x 8 elems.
//   value = Wcomb[k = kk*32 + (lane>>4)*8 + i][c = g*128 + w*16 + (lane&15)]
//   Wcomb rows: k<128 -> w_ih[k][c], else w_hh[k-128][c]
// Wc2: 16 frags (F = cb*4 + kk) x 64 x 8; value = W_cls[k][col = cb*16 + (lane&15)]
__global__ void prepack_kernel(const float* __restrict__ w_ih, const float* __restrict__ w_hh,
                               const float* __restrict__ W_cls,
                               unsigned short* __restrict__ Wt2, unsigned short* __restrict__ Wc2) {
  int tid = blockIdx.x * blockDim.x + threadIdx.x;
  int stride = gridDim.x * blockDim.x;
  for (int idx = tid; idx < 256 * 512; idx += stride) {
    int i = idx & 7;
    int lane = (idx >> 3) & 63;
    int F = idx >> 9;
    int w = F >> 5, g = (F >> 3) & 3, kk = F & 7;
    int c = g * 128 + w * 16 + (lane & 15);
    int k = kk * 32 + (lane >> 4) * 8 + i;
    float v = (k < 128) ? w_ih[k * 512 + c] : w_hh[(k - 128) * 512 + c];
    Wt2[idx] = f2bf(v);
  }
  for (int idx = tid; idx < 16 * 512; idx += stride) {
    int i = idx & 7;
    int lane = (idx >> 3) & 63;
    int F = idx >> 9;
    int cb = F >> 2, kk = F & 3;
    int col = cb * 16 + (lane & 15);
    int k = kk * 32 + (lane >> 4) * 8 + i;
    Wc2[idx] = f2bf(W_cls[k * 64 + col]);
  }
}

// ---------------- CSR build ----------------
__global__ void count_kernel(const int* __restrict__ dst, int* __restrict__ cnt) {
  int e = blockIdx.x * blockDim.x + threadIdx.x;
  if (e < N_EDGES) atomicAdd(&cnt[dst[e]], 1);
}

__global__ __launch_bounds__(256) void scan1_kernel(const int* __restrict__ cnt,
                                                    int* __restrict__ lexcl, int* __restrict__ btot) {
  __shared__ int sh[256];
  int tid = threadIdx.x;
  int base = blockIdx.x * 1024 + tid * 4;
  int v[4];
  #pragma unroll
  for (int q = 0; q < 4; q++) {
    int i = base + q;
    v[q] = (i < N_NODES) ? cnt[i] : 0;
  }
  int tsum = v[0] + v[1] + v[2] + v[3];
  sh[tid] = tsum;
  __syncthreads();
  int val = tsum;
  for (int off = 1; off < 256; off <<= 1) {
    int x = (tid >= off) ? sh[tid - off] : 0;
    __syncthreads();
    val += x;
    sh[tid] = val;
    __syncthreads();
  }
  int ex = val - tsum;  // exclusive
  if (tid == 255) btot[blockIdx.x] = val;
  #pragma unroll
  for (int q = 0; q < 4; q++) {
    int i = base + q;
    if (i < N_NODES) lexcl[i] = ex;
    ex += v[q];
  }
}

__global__ void scan2_kernel(const int* __restrict__ btot, int* __restrict__ bbase) {
  if (threadIdx.x == 0 && blockIdx.x == 0) {
    int run = 0;
    for (int b = 0; b < NB_SCAN; b++) { bbase[b] = run; run += btot[b]; }
  }
}

__global__ void scan3_kernel(const int* __restrict__ lexcl, const int* __restrict__ bbase,
                             int* __restrict__ rowstart, int* __restrict__ cursor) {
  int i = blockIdx.x * blockDim.x + threadIdx.x;
  if (i < N_NODES) {
    int rs = lexcl[i] + bbase[i >> 10];
    rowstart[i] = rs;
    cursor[i] = rs;
  }
}

__global__ void fill_kernel(const int* __restrict__ src, const int* __restrict__ dst,
                            int* __restrict__ cursor, int* __restrict__ esrc) {
  int e = blockIdx.x * blockDim.x + threadIdx.x;
  if (e < N_EDGES) {
    int d = dst[e];
    int pos = atomicAdd(&cursor[d], 1);
    esrc[pos] = src[e];
  }
}

// ---------------- h_struct = nf@W_self + mean_neigh@W_neigh + b (fused gather) ----------------
#define HS_TILE 32
__global__ __launch_bounds__(256) void hstruct_kernel(
    const float* __restrict__ nf, const int* __restrict__ esrc,
    const int* __restrict__ rowstart, const int* __restrict__ cnt,
    const float* __restrict__ Wself, const float* __restrict__ Wneigh, const float* __restrict__ bs,
    float* __restrict__ hstruct) {
  __shared__ float s_nf[HS_TILE][IN_DIM + 1];
  __shared__ float s_hn[HS_TILE][IN_DIM + 1];
  int tid = threadIdx.x;
  int node0 = blockIdx.x * HS_TILE;
  for (int i = tid; i < HS_TILE * IN_DIM; i += 256) {
    int r = i >> 6, k = i & 63;
    int node = node0 + r;
    s_nf[r][k] = (node < N_NODES) ? nf[node * 64 + k] : 0.f;
  }
  int wv = tid >> 6, lane = tid & 63;
  for (int r = wv; r < HS_TILE; r += 4) {
    int node = node0 + r;
    float acc = 0.f;
    int n = 0;
    if (node < N_NODES) {
      n = cnt[node];
      int st = rowstart[node];
      for (int j = 0; j < n; j++) {
        int s = esrc[st + j];
        acc += nf[s * 64 + lane];
      }
    }
    s_hn[r][lane] = acc / fmaxf((float)n, 1.f);
  }
  __syncthreads();
  int r = tid & 31;
  int c0 = (tid >> 5) * 16;
  float accs[16];
  #pragma unroll
  for (int i = 0; i < 16; i++) accs[i] = 0.f;
  for (int k = 0; k < IN_DIM; k++) {
    float a = s_nf[r][k];
    float b = s_hn[r][k];
    const float4* ws = (const float4*)&Wself[k * HID + c0];
    const float4* wn = (const float4*)&Wneigh[k * HID + c0];
    #pragma unroll
    for (int q = 0; q < 4; q++) {
      float4 w1 = ws[q]; float4 w2 = wn[q];
      accs[q*4+0] += a * w1.x + b * w2.x;
      accs[q*4+1] += a * w1.y + b * w2.y;
      accs[q*4+2] += a * w1.z + b * w2.z;
      accs[q*4+3] += a * w1.w + b * w2.w;
    }
  }
  int node = node0 + r;
  if (node < N_NODES) {
    #pragma unroll
    for (int i = 0; i < 16; i++)
      hstruct[(size_t)node * HID + c0 + i] = accs[i] + bs[c0 + i];
  }
}

// ---------------- fused LSTM (8 steps) + classifier, W in registers ----------------
// 512 threads = 8 waves, 64 nodes/block. Wave w owns hidden cols jj in [16w,16w+16),
// all 4 gates -> cell update fully in-lane. B-frags (32 x short8 = 128 VGPR) persist.
#define LB 64
__global__ __launch_bounds__(512, 2) void lstm_kernel(
    const float* __restrict__ hist,          // [N][8][128] f32
    const unsigned short* __restrict__ Wt2,  // frag-ordered bf16
    const unsigned short* __restrict__ Wc2,  // frag-ordered bf16
    const float* __restrict__ b_lstm,        // [512]
    const float* __restrict__ hstruct,       // [N][128]
    const float* __restrict__ b_cls,         // [64]
    float* __restrict__ out)                 // [N][64]
{
  __shared__ alignas(16) unsigned short Abuf[64 * 256];  // 32KB, [row][swz(kb)][8]

  const int tid = threadIdx.x;
  const int lane = tid & 63;
  const int w = tid >> 6;
  const int l15 = lane & 15;
  const int l4 = lane >> 4;
  const int base = blockIdx.x * LB;
  const int jj = w * 16 + l15;     // hidden unit owned by this lane

  // persistent B fragments: Bfr[g][kk]
  short8 Bfr[4][8];
  #pragma unroll
  for (int g = 0; g < 4; g++)
    #pragma unroll
    for (int kk = 0; kk < 8; kk++)
      Bfr[g][kk] = *(const short8*)&Wt2[((w * 32 + g * 8 + kk) * 64 + lane) * 8];

  const float bi  = b_lstm[jj];
  const float bf_ = b_lstm[128 + jj];
  const float bg  = b_lstm[256 + jj];
  const float bo  = b_lstm[384 + jj];

  float c_st[16], h_reg[16];
  #pragma unroll
  for (int i = 0; i < 16; i++) { c_st[i] = 0.f; h_reg[i] = 0.f; }

  // zero h-region (k 128..255)
  for (int u = tid; u < 64 * 16; u += 512) {
    int row = u >> 4;
    int kbh = u & 15;
    short8 z = {0,0,0,0,0,0,0,0};
    *(short8*)&Abuf[row * 256 + 128 + kbh * 8] = z;
  }

  auto stage_x = [&](int tt) {
    #pragma unroll
    for (int i2 = 0; i2 < 2; i2++) {
      int u = tid + (i2 << 9);
      int row = u >> 4;
      int kb = u & 15;
      int node = base + row;
      float4 x0 = make_float4(0.f,0.f,0.f,0.f), x1 = make_float4(0.f,0.f,0.f,0.f);
      if (node < N_NODES) {
        const float4* p = (const float4*)&hist[((size_t)node * T_HIST + tt) * HID + kb * 8];
        x0 = p[0]; x1 = p[1];
      }
      short8 v;
      v[0] = (short)f2bf(x0.x); v[1] = (short)f2bf(x0.y);
      v[2] = (short)f2bf(x0.z); v[3] = (short)f2bf(x0.w);
      v[4] = (short)f2bf(x1.x); v[5] = (short)f2bf(x1.y);
      v[6] = (short)f2bf(x1.z); v[7] = (short)f2bf(x1.w);
      int sb = (kb & 8) | ((kb & 7) ^ (row & 7));
      *(short8*)&Abuf[row * 256 + sb * 8] = v;
    }
  };

  stage_x(0);
  __syncthreads();

  for (int t = 0; t < T_HIST; t++) {
    f32x4 acc[4][4];
    #pragma unroll
    for (int rb = 0; rb < 4; rb++)
      #pragma unroll
      for (int g = 0; g < 4; g++) {
        f32x4 z = {0.f,0.f,0.f,0.f};
        acc[rb][g] = z;
      }

    #pragma unroll
    for (int kk = 0; kk < 8; kk++) {
      #pragma unroll
      for (int rb = 0; rb < 4; rb++) {
        int row = rb * 16 + l15;
        int kb = kk * 4 + l4;
        int sb = (kb & 24) | ((kb & 7) ^ (row & 7));
        short8 a = *(const short8*)&Abuf[row * 256 + sb * 8];
        #pragma unroll
        for (int g = 0; g < 4; g++)
          acc[rb][g] = __builtin_amdgcn_mfma_f32_16x16x32_bf16(a, Bfr[g][kk], acc[rb][g], 0, 0, 0);
      }
    }
    __syncthreads();  // all A reads done -> safe to overwrite x and h regions

    if (t < T_HIST - 1) stage_x(t + 1);

    #pragma unroll
    for (int rb = 0; rb < 4; rb++) {
      #pragma unroll
      for (int reg = 0; reg < 4; reg++) {
        int r = rb * 4 + reg;
        float gi = sigm(acc[rb][0][reg] + bi);
        float gf = sigm(acc[rb][1][reg] + bf_);
        float gg = tanh_f(acc[rb][2][reg] + bg);
        float go = sigm(acc[rb][3][reg] + bo);
        float c = gf * c_st[r] + gi * gg;
        c_st[r] = c;
        float h = go * tanh_f(c);
        h_reg[r] = h;
        if (t < T_HIST - 1) {
          int row = rb * 16 + l4 * 4 + reg;
          int kb = 16 + (jj >> 3);
          int sb = (kb & 24) | ((kb & 7) ^ (row & 7));
          Abuf[row * 256 + sb * 8 + (jj & 7)] = f2bf(h);
        }
      }
    }
    if (t < T_HIST - 1) __syncthreads();  // A(t+1) ready
  }

  // ---------------- epilogue: out = (h_struct + h)@W_cls + b_cls ----------------
  // write comb into x-region
  #pragma unroll
  for (int rb = 0; rb < 4; rb++) {
    #pragma unroll
    for (int reg = 0; reg < 4; reg++) {
      int row = rb * 16 + l4 * 4 + reg;
      int node = base + row;
      float hs = (node < N_NODES) ? hstruct[(size_t)node * HID + jj] : 0.f;
      float comb = hs + h_reg[rb * 4 + reg];
      int kb = jj >> 3;
      int sb = (kb & 8) | ((kb & 7) ^ (row & 7));
      Abuf[row * 256 + sb * 8 + (jj & 7)] = f2bf(comb);
    }
  }
  // Wc fragments (B regs dead now)
  short8 bc[2][4];
  #pragma unroll
  for (int fi = 0; fi < 2; fi++) {
    int f = w * 2 + fi;
    int cbo = f & 3;
    #pragma unroll
    for (int kk = 0; kk < 4; kk++)
      bc[fi][kk] = *(const short8*)&Wc2[((cbo * 4 + kk) * 64 + lane) * 8];
  }
  __syncthreads();

  #pragma unroll
  for (int fi = 0; fi < 2; fi++) {
    int f = w * 2 + fi;
    int rbo = f >> 2, cbo = f & 3;
    f32x4 o = {0.f,0.f,0.f,0.f};
    #pragma unroll
    for (int kk = 0; kk < 4; kk++) {
      int row = rbo * 16 + l15;
      int kb = kk * 4 + l4;
      int sb = (kb & 8) | ((kb & 7) ^ (row & 7));
      short8 a = *(const short8*)&Abuf[row * 256 + sb * 8];
      o = __builtin_amdgcn_mfma_f32_16x16x32_bf16(a, bc[fi][kk], o, 0, 0, 0);
    }
    int col = cbo * 16 + l15;
    float bcl = b_cls[col];
    #pragma unroll
    for (int reg = 0; reg < 4; reg++) {
      int row = rbo * 16 + l4 * 4 + reg;
      int node = base + row;
      if (node < N_NODES) out[(size_t)node * OUT_DIM + col] = o[reg] + bcl;
    }
  }
}

// ---------------- launch ----------------
extern "C" void kernel_launch(void* const* d_in, const int* in_sizes, int n_in,
                              void* d_out, int out_size, void* d_ws, size_t ws_size,
                              hipStream_t stream) {
  (void)in_sizes; (void)n_in; (void)out_size; (void)ws_size;
  const float* node_feats = (const float*)d_in[0];
  const float* hist       = (const float*)d_in[1];
  const int*   src        = (const int*)d_in[2];
  const int*   dst        = (const int*)d_in[3];
  const float* W_self     = (const float*)d_in[4];
  const float* W_neigh    = (const float*)d_in[5];
  const float* b_sage     = (const float*)d_in[6];
  const float* w_ih       = (const float*)d_in[7];
  const float* w_hh       = (const float*)d_in[8];
  const float* b_lstm     = (const float*)d_in[9];
  const float* W_cls      = (const float*)d_in[10];
  const float* b_cls      = (const float*)d_in[11];
  float* out = (float*)d_out;

  char* ws = (char*)d_ws;
  int* cnt        = (int*)(ws);                    // 200,000 -> pad 200,192
  int* lexcl      = (int*)(ws + 200192);           // 200,000 -> 400,384
  int* rowstart   = (int*)(ws + 400384);           // 200,000 -> 600,576
  int* cursor     = (int*)(ws + 600576);           // 200,000 -> 800,768
  int* btot       = (int*)(ws + 800768);           // 256
  int* bbase      = (int*)(ws + 801024);           // 256
  int* esrc       = (int*)(ws + 801280);           // 3,200,000 -> 4,001,280
  float* hstruct  = (float*)(ws + 4001280);        // 25,600,000 -> 29,601,280
  unsigned short* Wt2 = (unsigned short*)(ws + 29601280);  // 262,144
  unsigned short* Wc2 = (unsigned short*)(ws + 29863424);  // 16,384

  hipMemsetAsync(cnt, 0, 200000, stream);
  prepack_kernel<<<64, 256, 0, stream>>>(w_ih, w_hh, W_cls, Wt2, Wc2);
  count_kernel<<<(N_EDGES + 255) / 256, 256, 0, stream>>>(dst, cnt);
  scan1_kernel<<<NB_SCAN, 256, 0, stream>>>(cnt, lexcl, btot);
  scan2_kernel<<<1, 64, 0, stream>>>(btot, bbase);
  scan3_kernel<<<(N_NODES + 255) / 256, 256, 0, stream>>>(lexcl, bbase, rowstart, cursor);
  fill_kernel<<<(N_EDGES + 255) / 256, 256, 0, stream>>>(src, dst, cursor, esrc);
  hstruct_kernel<<<(N_NODES + HS_TILE - 1) / HS_TILE, 256, 0, stream>>>(
      node_feats, esrc, rowstart, cnt, W_self, W_neigh, b_sage, hstruct);
  lstm_kernel<<<(N_NODES + LB - 1) / LB, 512, 0, stream>>>(
      hist, Wt2, Wc2, b_lstm, hstruct, b_cls, out);
}

// Round 3
// 604.753 us; speedup vs baseline: 1.5522x; 1.2672x over previous
//
#include <hip/hip_runtime.h>
#include <hip/hip_bf16.h>
#include <stdint.h>

#define N_NODES 50000
#define N_EDGES 800000
#define IN_DIM 64
#define HID 128
#define OUT_DIM 64
#define T_HIST 8

#define NB_SCAN ((N_NODES + 1023) / 1024)   // 49

typedef __attribute__((ext_vector_type(8))) short short8;
typedef __attribute__((ext_vector_type(4))) float f32x4;

__device__ __forceinline__ unsigned short f2bf(float x) {
  unsigned int u = __builtin_bit_cast(unsigned int, x);
  unsigned int r = (u + 0x7FFFu + ((u >> 16) & 1u)) >> 16;
  return (unsigned short)r;
}
// sigmoid(x) = 1/(1+2^(-x*log2e)); safe at +-inf, no clamps, rcp-based
__device__ __forceinline__ float sigm(float x) {
  float e = __builtin_amdgcn_exp2f(-1.4426950408889634f * x);
  return __builtin_amdgcn_rcpf(1.f + e);
}
// tanh(x) = 1 - 2/(2^(2x*log2e)+1); safe at +-inf
__device__ __forceinline__ float tanh_f(float x) {
  float e = __builtin_amdgcn_exp2f(2.8853900817779268f * x);
  return 1.f - 2.f * __builtin_amdgcn_rcpf(e + 1.f);
}

// ---------------- prepack: fragment-ordered bf16 weights ----------------
// Wt2: 256 frags (F = w*32 + g*8 + kk) x 64 lanes x 8 elems.
//   value = Wcomb[k = kk*32 + (lane>>4)*8 + i][c = g*128 + w*16 + (lane&15)]
// Wc2: 16 frags (F = cb*4 + kk) x 64 x 8; value = W_cls[k][col = cb*16 + (lane&15)]
__global__ void prepack_kernel(const float* __restrict__ w_ih, const float* __restrict__ w_hh,
                               const float* __restrict__ W_cls,
                               unsigned short* __restrict__ Wt2, unsigned short* __restrict__ Wc2) {
  int tid = blockIdx.x * blockDim.x + threadIdx.x;
  int stride = gridDim.x * blockDim.x;
  for (int idx = tid; idx < 256 * 512; idx += stride) {
    int i = idx & 7;
    int lane = (idx >> 3) & 63;
    int F = idx >> 9;
    int w = F >> 5, g = (F >> 3) & 3, kk = F & 7;
    int c = g * 128 + w * 16 + (lane & 15);
    int k = kk * 32 + (lane >> 4) * 8 + i;
    float v = (k < 128) ? w_ih[k * 512 + c] : w_hh[(k - 128) * 512 + c];
    Wt2[idx] = f2bf(v);
  }
  for (int idx = tid; idx < 16 * 512; idx += stride) {
    int i = idx & 7;
    int lane = (idx >> 3) & 63;
    int F = idx >> 9;
    int cb = F >> 2, kk = F & 3;
    int col = cb * 16 + (lane & 15);
    int k = kk * 32 + (lane >> 4) * 8 + i;
    Wc2[idx] = f2bf(W_cls[k * 64 + col]);
  }
}

// ---------------- CSR build ----------------
__global__ void count_kernel(const int* __restrict__ dst, int* __restrict__ cnt) {
  int e = blockIdx.x * blockDim.x + threadIdx.x;
  if (e < N_EDGES) atomicAdd(&cnt[dst[e]], 1);
}

__global__ __launch_bounds__(256) void scan1_kernel(const int* __restrict__ cnt,
                                                    int* __restrict__ lexcl, int* __restrict__ btot) {
  __shared__ int sh[256];
  int tid = threadIdx.x;
  int base = blockIdx.x * 1024 + tid * 4;
  int v[4];
  #pragma unroll
  for (int q = 0; q < 4; q++) {
    int i = base + q;
    v[q] = (i < N_NODES) ? cnt[i] : 0;
  }
  int tsum = v[0] + v[1] + v[2] + v[3];
  sh[tid] = tsum;
  __syncthreads();
  int val = tsum;
  for (int off = 1; off < 256; off <<= 1) {
    int x = (tid >= off) ? sh[tid - off] : 0;
    __syncthreads();
    val += x;
    sh[tid] = val;
    __syncthreads();
  }
  int ex = val - tsum;  // exclusive
  if (tid == 255) btot[blockIdx.x] = val;
  #pragma unroll
  for (int q = 0; q < 4; q++) {
    int i = base + q;
    if (i < N_NODES) lexcl[i] = ex;
    ex += v[q];
  }
}

__global__ void scan2_kernel(const int* __restrict__ btot, int* __restrict__ bbase) {
  if (threadIdx.x == 0 && blockIdx.x == 0) {
    int run = 0;
    for (int b = 0; b < NB_SCAN; b++) { bbase[b] = run; run += btot[b]; }
  }
}

__global__ void scan3_kernel(const int* __restrict__ lexcl, const int* __restrict__ bbase,
                             int* __restrict__ rowstart, int* __restrict__ cursor) {
  int i = blockIdx.x * blockDim.x + threadIdx.x;
  if (i < N_NODES) {
    int rs = lexcl[i] + bbase[i >> 10];
    rowstart[i] = rs;
    cursor[i] = rs;
  }
}

__global__ void fill_kernel(const int* __restrict__ src, const int* __restrict__ dst,
                            int* __restrict__ cursor, int* __restrict__ esrc) {
  int e = blockIdx.x * blockDim.x + threadIdx.x;
  if (e < N_EDGES) {
    int d = dst[e];
    int pos = atomicAdd(&cursor[d], 1);
    esrc[pos] = src[e];
  }
}

// ---------------- h_struct = nf@W_self + mean_neigh@W_neigh + b (fused gather) ----------------
#define HS_TILE 32
__global__ __launch_bounds__(256) void hstruct_kernel(
    const float* __restrict__ nf, const int* __restrict__ esrc,
    const int* __restrict__ rowstart, const int* __restrict__ cnt,
    const float* __restrict__ Wself, const float* __restrict__ Wneigh, const float* __restrict__ bs,
    float* __restrict__ hstruct) {
  __shared__ float s_nf[HS_TILE][IN_DIM + 1];
  __shared__ float s_hn[HS_TILE][IN_DIM + 1];
  int tid = threadIdx.x;
  int node0 = blockIdx.x * HS_TILE;
  for (int i = tid; i < HS_TILE * IN_DIM; i += 256) {
    int r = i >> 6, k = i & 63;
    int node = node0 + r;
    s_nf[r][k] = (node < N_NODES) ? nf[node * 64 + k] : 0.f;
  }
  int wv = tid >> 6, lane = tid & 63;
  for (int r = wv; r < HS_TILE; r += 4) {
    int node = node0 + r;
    float a0 = 0.f, a1 = 0.f, a2 = 0.f, a3 = 0.f;
    int n = 0;
    if (node < N_NODES) {
      n = cnt[node];
      int st = rowstart[node];
      int j = 0;
      for (; j + 4 <= n; j += 4) {
        int s0 = esrc[st + j], s1 = esrc[st + j + 1];
        int s2 = esrc[st + j + 2], s3 = esrc[st + j + 3];
        a0 += nf[s0 * 64 + lane];
        a1 += nf[s1 * 64 + lane];
        a2 += nf[s2 * 64 + lane];
        a3 += nf[s3 * 64 + lane];
      }
      for (; j < n; j++) a0 += nf[esrc[st + j] * 64 + lane];
    }
    s_hn[r][lane] = (a0 + a1 + a2 + a3) * __builtin_amdgcn_rcpf(fmaxf((float)n, 1.f));
  }
  __syncthreads();
  int r = tid & 31;
  int c0 = (tid >> 5) * 16;
  float accs[16];
  #pragma unroll
  for (int i = 0; i < 16; i++) accs[i] = 0.f;
  for (int k = 0; k < IN_DIM; k++) {
    float a = s_nf[r][k];
    float b = s_hn[r][k];
    const float4* ws = (const float4*)&Wself[k * HID + c0];
    const float4* wn = (const float4*)&Wneigh[k * HID + c0];
    #pragma unroll
    for (int q = 0; q < 4; q++) {
      float4 w1 = ws[q]; float4 w2 = wn[q];
      accs[q*4+0] += a * w1.x + b * w2.x;
      accs[q*4+1] += a * w1.y + b * w2.y;
      accs[q*4+2] += a * w1.z + b * w2.z;
      accs[q*4+3] += a * w1.w + b * w2.w;
    }
  }
  int node = node0 + r;
  if (node < N_NODES) {
    #pragma unroll
    for (int i = 0; i < 16; i++)
      hstruct[(size_t)node * HID + c0 + i] = accs[i] + bs[c0 + i];
  }
}

// ---------------- fused LSTM (8 steps) + classifier, W in registers ----------------
// 512 threads = 8 waves, 64 nodes/block. Wave w owns gate cols jj in [16w,16w+16)
// for all 4 gates -> cell update fully in-lane. A double-buffered: 1 barrier/step.
#define LB 64
__global__ __launch_bounds__(512, 2) void lstm_kernel(
    const float* __restrict__ hist,          // [N][8][128] f32
    const unsigned short* __restrict__ Wt2,  // frag-ordered bf16
    const unsigned short* __restrict__ Wc2,  // frag-ordered bf16
    const float* __restrict__ b_lstm,        // [512]
    const float* __restrict__ hstruct,       // [N][128]
    const float* __restrict__ b_cls,         // [64]
    float* __restrict__ out)                 // [N][64]
{
  __shared__ alignas(16) unsigned short Abuf[2][64 * 256];  // 2 x 32KB, [row][swz(kb)][8]

  const int tid = threadIdx.x;
  const int lane = tid & 63;
  const int w = tid >> 6;
  const int l15 = lane & 15;
  const int l4 = lane >> 4;
  const int base = blockIdx.x * LB;
  const int jj = w * 16 + l15;     // hidden unit owned by this lane

  // persistent B fragments: Bfr[g][kk]  (128 VGPR)
  short8 Bfr[4][8];
  #pragma unroll
  for (int g = 0; g < 4; g++)
    #pragma unroll
    for (int kk = 0; kk < 8; kk++)
      Bfr[g][kk] = *(const short8*)&Wt2[((w * 32 + g * 8 + kk) * 64 + lane) * 8];

  const float bi  = b_lstm[jj];
  const float bf_ = b_lstm[128 + jj];
  const float bg  = b_lstm[256 + jj];
  const float bo  = b_lstm[384 + jj];

  float c_st[16];
  #pragma unroll
  for (int i = 0; i < 16; i++) c_st[i] = 0.f;

  // prologue: zero h-region of buf0, stage x(0) into buf0
  for (int u = tid; u < 64 * 16; u += 512) {
    int row = u >> 4;
    int kbh = u & 15;
    short8 z = {0,0,0,0,0,0,0,0};
    *(short8*)&Abuf[0][row * 256 + 128 + kbh * 8] = z;
  }
  #pragma unroll
  for (int i2 = 0; i2 < 2; i2++) {
    int u = tid + (i2 << 9);
    int row = u >> 4;
    int kb = u & 15;
    int node = base + row;
    float4 x0 = make_float4(0.f,0.f,0.f,0.f), x1 = make_float4(0.f,0.f,0.f,0.f);
    if (node < N_NODES) {
      const float4* p = (const float4*)&hist[(size_t)node * (T_HIST * HID) + kb * 8];
      x0 = p[0]; x1 = p[1];
    }
    short8 v;
    v[0] = (short)f2bf(x0.x); v[1] = (short)f2bf(x0.y);
    v[2] = (short)f2bf(x0.z); v[3] = (short)f2bf(x0.w);
    v[4] = (short)f2bf(x1.x); v[5] = (short)f2bf(x1.y);
    v[6] = (short)f2bf(x1.z); v[7] = (short)f2bf(x1.w);
    int sb = (kb & 8) | ((kb & 7) ^ (row & 7));
    *(short8*)&Abuf[0][row * 256 + sb * 8] = v;
  }
  __syncthreads();

  float4 xp[4];  // prefetch regs (16 VGPR)

  #pragma unroll
  for (int t = 0; t < T_HIST; t++) {
    unsigned short* Acur = &Abuf[t & 1][0];
    unsigned short* Anxt = &Abuf[(t & 1) ^ 1][0];

    // issue x(t+1) global loads early: latency hides under MFMA phase
    if (t < T_HIST - 1) {
      #pragma unroll
      for (int i2 = 0; i2 < 2; i2++) {
        int u = tid + (i2 << 9);
        int row = u >> 4;
        int kb = u & 15;
        int node = base + row;
        if (node < N_NODES) {
          const float4* p = (const float4*)&hist[(size_t)node * (T_HIST * HID) + (t + 1) * HID + kb * 8];
          xp[i2 * 2]     = p[0];
          xp[i2 * 2 + 1] = p[1];
        } else {
          xp[i2 * 2]     = make_float4(0.f,0.f,0.f,0.f);
          xp[i2 * 2 + 1] = make_float4(0.f,0.f,0.f,0.f);
        }
      }
    }

    f32x4 acc[4][4];
    #pragma unroll
    for (int rb = 0; rb < 4; rb++)
      #pragma unroll
      for (int g = 0; g < 4; g++) {
        f32x4 z = {0.f,0.f,0.f,0.f};
        acc[rb][g] = z;
      }

    #pragma unroll
    for (int kk = 0; kk < 8; kk++) {
      #pragma unroll
      for (int rb = 0; rb < 4; rb++) {
        int row = rb * 16 + l15;
        int kb = kk * 4 + l4;
        int sb = (kb & 24) | ((kb & 7) ^ (row & 7));
        short8 a = *(const short8*)&Acur[row * 256 + sb * 8];
        #pragma unroll
        for (int g = 0; g < 4; g++)
          acc[rb][g] = __builtin_amdgcn_mfma_f32_16x16x32_bf16(a, Bfr[g][kk], acc[rb][g], 0, 0, 0);
      }
    }

    if (t < T_HIST - 1) {
      // cell update in-register; write h(t) to next buffer's h-region
      #pragma unroll
      for (int rb = 0; rb < 4; rb++) {
        #pragma unroll
        for (int reg = 0; reg < 4; reg++) {
          int r = rb * 4 + reg;
          float gi = sigm(acc[rb][0][reg] + bi);
          float gf = sigm(acc[rb][1][reg] + bf_);
          float gg = tanh_f(acc[rb][2][reg] + bg);
          float go = sigm(acc[rb][3][reg] + bo);
          float c = gf * c_st[r] + gi * gg;
          c_st[r] = c;
          float h = go * tanh_f(c);
          int row = rb * 16 + l4 * 4 + reg;
          int kb = 16 + (jj >> 3);
          int sb = (kb & 24) | ((kb & 7) ^ (row & 7));
          Anxt[row * 256 + sb * 8 + (jj & 7)] = f2bf(h);
        }
      }
      // write staged x(t+1) into next buffer's x-region
      #pragma unroll
      for (int i2 = 0; i2 < 2; i2++) {
        int u = tid + (i2 << 9);
        int row = u >> 4;
        int kb = u & 15;
        float4 a0 = xp[i2 * 2], a1 = xp[i2 * 2 + 1];
        short8 v;
        v[0] = (short)f2bf(a0.x); v[1] = (short)f2bf(a0.y);
        v[2] = (short)f2bf(a0.z); v[3] = (short)f2bf(a0.w);
        v[4] = (short)f2bf(a1.x); v[5] = (short)f2bf(a1.y);
        v[6] = (short)f2bf(a1.z); v[7] = (short)f2bf(a1.w);
        int sb = (kb & 8) | ((kb & 7) ^ (row & 7));
        *(short8*)&Anxt[row * 256 + sb * 8] = v;
      }
      __syncthreads();   // single barrier per step
    } else {
      // ---- t == 7: epilogue. Bfr dead after the MFMA loop above. ----
      // issue hstruct + Wc + b_cls loads first (overlap with gate VALU)
      float hs[16];
      #pragma unroll
      for (int rb = 0; rb < 4; rb++) {
        #pragma unroll
        for (int reg = 0; reg < 4; reg++) {
          int row = rb * 16 + l4 * 4 + reg;
          int node = base + row;
          hs[rb * 4 + reg] = (node < N_NODES) ? hstruct[(size_t)node * HID + jj] : 0.f;
        }
      }
      short8 bc[2][4];
      #pragma unroll
      for (int fi = 0; fi < 2; fi++) {
        int f = w * 2 + fi;
        int cbo = f & 3;
        #pragma unroll
        for (int kk = 0; kk < 4; kk++)
          bc[fi][kk] = *(const short8*)&Wc2[((cbo * 4 + kk) * 64 + lane) * 8];
      }
      // cell update; comb = hstruct + h -> x-region of Anxt (= Abuf[0], free)
      #pragma unroll
      for (int rb = 0; rb < 4; rb++) {
        #pragma unroll
        for (int reg = 0; reg < 4; reg++) {
          int r = rb * 4 + reg;
          float gi = sigm(acc[rb][0][reg] + bi);
          float gf = sigm(acc[rb][1][reg] + bf_);
          float gg = tanh_f(acc[rb][2][reg] + bg);
          float go = sigm(acc[rb][3][reg] + bo);
          float c = gf * c_st[r] + gi * gg;
          float h = go * tanh_f(c);
          float comb = hs[r] + h;
          int row = rb * 16 + l4 * 4 + reg;
          int kb = jj >> 3;
          int sb = (kb & 8) | ((kb & 7) ^ (row & 7));
          Anxt[row * 256 + sb * 8 + (jj & 7)] = f2bf(comb);
        }
      }
      __syncthreads();

      // classifier: out = comb @ W_cls + b_cls
      #pragma unroll
      for (int fi = 0; fi < 2; fi++) {
        int f = w * 2 + fi;
        int rbo = f >> 2, cbo = f & 3;
        f32x4 o = {0.f,0.f,0.f,0.f};
        #pragma unroll
        for (int kk = 0; kk < 4; kk++) {
          int row = rbo * 16 + l15;
          int kb = kk * 4 + l4;
          int sb = (kb & 8) | ((kb & 7) ^ (row & 7));
          short8 a = *(const short8*)&Anxt[row * 256 + sb * 8];
          o = __builtin_amdgcn_mfma_f32_16x16x32_bf16(a, bc[fi][kk], o, 0, 0, 0);
        }
        int col = cbo * 16 + l15;
        float bcl = b_cls[col];
        #pragma unroll
        for (int reg = 0; reg < 4; reg++) {
          int row = rbo * 16 + l4 * 4 + reg;
          int node = base + row;
          if (node < N_NODES) out[(size_t)node * OUT_DIM + col] = o[reg] + bcl;
        }
      }
    }
  }
}

// ---------------- launch ----------------
extern "C" void kernel_launch(void* const* d_in, const int* in_sizes, int n_in,
                              void* d_out, int out_size, void* d_ws, size_t ws_size,
                              hipStream_t stream) {
  (void)in_sizes; (void)n_in; (void)out_size; (void)ws_size;
  const float* node_feats = (const float*)d_in[0];
  const float* hist       = (const float*)d_in[1];
  const int*   src        = (const int*)d_in[2];
  const int*   dst        = (const int*)d_in[3];
  const float* W_self     = (const float*)d_in[4];
  const float* W_neigh    = (const float*)d_in[5];
  const float* b_sage     = (const float*)d_in[6];
  const float* w_ih       = (const float*)d_in[7];
  const float* w_hh       = (const float*)d_in[8];
  const float* b_lstm     = (const float*)d_in[9];
  const float* W_cls      = (const float*)d_in[10];
  const float* b_cls      = (const float*)d_in[11];
  float* out = (float*)d_out;

  char* ws = (char*)d_ws;
  int* cnt        = (int*)(ws);                    // 200,000 -> pad 200,192
  int* lexcl      = (int*)(ws + 200192);           // 200,000 -> 400,384
  int* rowstart   = (int*)(ws + 400384);           // 200,000 -> 600,576
  int* cursor     = (int*)(ws + 600576);           // 200,000 -> 800,768
  int* btot       = (int*)(ws + 800768);           // 256
  int* bbase      = (int*)(ws + 801024);           // 256
  int* esrc       = (int*)(ws + 801280);           // 3,200,000 -> 4,001,280
  float* hstruct  = (float*)(ws + 4001280);        // 25,600,000 -> 29,601,280
  unsigned short* Wt2 = (unsigned short*)(ws + 29601280);  // 262,144
  unsigned short* Wc2 = (unsigned short*)(ws + 29863424);  // 16,384

  hipMemsetAsync(cnt, 0, 200000, stream);
  prepack_kernel<<<64, 256, 0, stream>>>(w_ih, w_hh, W_cls, Wt2, Wc2);
  count_kernel<<<(N_EDGES + 255) / 256, 256, 0, stream>>>(dst, cnt);
  scan1_kernel<<<NB_SCAN, 256, 0, stream>>>(cnt, lexcl, btot);
  scan2_kernel<<<1, 64, 0, stream>>>(btot, bbase);
  scan3_kernel<<<(N_NODES + 255) / 256, 256, 0, stream>>>(lexcl, bbase, rowstart, cursor);
  fill_kernel<<<(N_EDGES + 255) / 256, 256, 0, stream>>>(src, dst, cursor, esrc);
  hstruct_kernel<<<(N_NODES + HS_TILE - 1) / HS_TILE, 256, 0, stream>>>(
      node_feats, esrc, rowstart, cnt, W_self, W_neigh, b_sage, hstruct);
  lstm_kernel<<<(N_NODES + LB - 1) / LB, 512, 0, stream>>>(
      hist, Wt2, Wc2, b_lstm, hstruct, b_cls, out);
}

// Round 4
// 422.320 us; speedup vs baseline: 2.2227x; 1.4320x over previous
//
#include <hip/hip_runtime.h>
#include <hip/hip_bf16.h>
#include <stdint.h>

#define N_NODES 50000
#define N_EDGES 800000
#define IN_DIM 64
#define HID 128
#define OUT_DIM 64
#define T_HIST 8

#define NB_SCAN ((N_NODES + 1023) / 1024)   // 49

typedef __attribute__((ext_vector_type(8))) short short8;
typedef __attribute__((ext_vector_type(4))) float f32x4;

__device__ __forceinline__ unsigned short f2bf(float x) {
  unsigned int u = __builtin_bit_cast(unsigned int, x);
  unsigned int r = (u + 0x7FFFu + ((u >> 16) & 1u)) >> 16;
  return (unsigned short)r;
}
// sigmoid(x) = 1/(1+2^(-x*log2e)); safe at +-inf, no clamps, rcp-based
__device__ __forceinline__ float sigm(float x) {
  float e = __builtin_amdgcn_exp2f(-1.4426950408889634f * x);
  return __builtin_amdgcn_rcpf(1.f + e);
}
// tanh(x) = 1 - 2/(2^(2x*log2e)+1); safe at +-inf
__device__ __forceinline__ float tanh_f(float x) {
  float e = __builtin_amdgcn_exp2f(2.8853900817779268f * x);
  return 1.f - 2.f * __builtin_amdgcn_rcpf(e + 1.f);
}

// ---------------- prepack: fragment-ordered bf16 weights ----------------
__global__ void prepack_kernel(const float* __restrict__ w_ih, const float* __restrict__ w_hh,
                               const float* __restrict__ W_cls,
                               unsigned short* __restrict__ Wt2, unsigned short* __restrict__ Wc2) {
  int tid = blockIdx.x * blockDim.x + threadIdx.x;
  int stride = gridDim.x * blockDim.x;
  for (int idx = tid; idx < 256 * 512; idx += stride) {
    int i = idx & 7;
    int lane = (idx >> 3) & 63;
    int F = idx >> 9;
    int w = F >> 5, g = (F >> 3) & 3, kk = F & 7;
    int c = g * 128 + w * 16 + (lane & 15);
    int k = kk * 32 + (lane >> 4) * 8 + i;
    float v = (k < 128) ? w_ih[k * 512 + c] : w_hh[(k - 128) * 512 + c];
    Wt2[idx] = f2bf(v);
  }
  for (int idx = tid; idx < 16 * 512; idx += stride) {
    int i = idx & 7;
    int lane = (idx >> 3) & 63;
    int F = idx >> 9;
    int cb = F >> 2, kk = F & 3;
    int col = cb * 16 + (lane & 15);
    int k = kk * 32 + (lane >> 4) * 8 + i;
    Wc2[idx] = f2bf(W_cls[k * 64 + col]);
  }
}

// ---------------- CSR build ----------------
__global__ void count_kernel(const int* __restrict__ dst, int* __restrict__ cnt) {
  int e = blockIdx.x * blockDim.x + threadIdx.x;
  if (e < N_EDGES) atomicAdd(&cnt[dst[e]], 1);
}

__global__ __launch_bounds__(256) void scan1_kernel(const int* __restrict__ cnt,
                                                    int* __restrict__ lexcl, int* __restrict__ btot) {
  __shared__ int sh[256];
  int tid = threadIdx.x;
  int base = blockIdx.x * 1024 + tid * 4;
  int v[4];
  #pragma unroll
  for (int q = 0; q < 4; q++) {
    int i = base + q;
    v[q] = (i < N_NODES) ? cnt[i] : 0;
  }
  int tsum = v[0] + v[1] + v[2] + v[3];
  sh[tid] = tsum;
  __syncthreads();
  int val = tsum;
  for (int off = 1; off < 256; off <<= 1) {
    int x = (tid >= off) ? sh[tid - off] : 0;
    __syncthreads();
    val += x;
    sh[tid] = val;
    __syncthreads();
  }
  int ex = val - tsum;  // exclusive
  if (tid == 255) btot[blockIdx.x] = val;
  #pragma unroll
  for (int q = 0; q < 4; q++) {
    int i = base + q;
    if (i < N_NODES) lexcl[i] = ex;
    ex += v[q];
  }
}

__global__ void scan2_kernel(const int* __restrict__ btot, int* __restrict__ bbase) {
  if (threadIdx.x == 0 && blockIdx.x == 0) {
    int run = 0;
    for (int b = 0; b < NB_SCAN; b++) { bbase[b] = run; run += btot[b]; }
  }
}

__global__ void scan3_kernel(const int* __restrict__ lexcl, const int* __restrict__ bbase,
                             int* __restrict__ rowstart, int* __restrict__ cursor) {
  int i = blockIdx.x * blockDim.x + threadIdx.x;
  if (i < N_NODES) {
    int rs = lexcl[i] + bbase[i >> 10];
    rowstart[i] = rs;
    cursor[i] = rs;
  }
}

__global__ void fill_kernel(const int* __restrict__ src, const int* __restrict__ dst,
                            int* __restrict__ cursor, int* __restrict__ esrc) {
  int e = blockIdx.x * blockDim.x + threadIdx.x;
  if (e < N_EDGES) {
    int d = dst[e];
    int pos = atomicAdd(&cursor[d], 1);
    esrc[pos] = src[e];
  }
}

// ---------------- h_struct = nf@W_self + mean_neigh@W_neigh + b (fused gather) ----------------
#define HS_TILE 32
__global__ __launch_bounds__(256) void hstruct_kernel(
    const float* __restrict__ nf, const int* __restrict__ esrc,
    const int* __restrict__ rowstart, const int* __restrict__ cnt,
    const float* __restrict__ Wself, const float* __restrict__ Wneigh, const float* __restrict__ bs,
    float* __restrict__ hstruct) {
  __shared__ float s_nf[HS_TILE][IN_DIM + 1];
  __shared__ float s_hn[HS_TILE][IN_DIM + 1];
  int tid = threadIdx.x;
  int node0 = blockIdx.x * HS_TILE;
  for (int i = tid; i < HS_TILE * IN_DIM; i += 256) {
    int r = i >> 6, k = i & 63;
    int node = node0 + r;
    s_nf[r][k] = (node < N_NODES) ? nf[node * 64 + k] : 0.f;
  }
  int wv = tid >> 6, lane = tid & 63;
  for (int r = wv; r < HS_TILE; r += 4) {
    int node = node0 + r;
    float a0 = 0.f, a1 = 0.f, a2 = 0.f, a3 = 0.f;
    int n = 0;
    if (node < N_NODES) {
      n = cnt[node];
      int st = rowstart[node];
      int j = 0;
      for (; j + 4 <= n; j += 4) {
        int s0 = esrc[st + j], s1 = esrc[st + j + 1];
        int s2 = esrc[st + j + 2], s3 = esrc[st + j + 3];
        a0 += nf[s0 * 64 + lane];
        a1 += nf[s1 * 64 + lane];
        a2 += nf[s2 * 64 + lane];
        a3 += nf[s3 * 64 + lane];
      }
      for (; j < n; j++) a0 += nf[esrc[st + j] * 64 + lane];
    }
    s_hn[r][lane] = (a0 + a1 + a2 + a3) * __builtin_amdgcn_rcpf(fmaxf((float)n, 1.f));
  }
  __syncthreads();
  int r = tid & 31;
  int c0 = (tid >> 5) * 16;
  float accs[16];
  #pragma unroll
  for (int i = 0; i < 16; i++) accs[i] = 0.f;
  for (int k = 0; k < IN_DIM; k++) {
    float a = s_nf[r][k];
    float b = s_hn[r][k];
    const float4* ws = (const float4*)&Wself[k * HID + c0];
    const float4* wn = (const float4*)&Wneigh[k * HID + c0];
    #pragma unroll
    for (int q = 0; q < 4; q++) {
      float4 w1 = ws[q]; float4 w2 = wn[q];
      accs[q*4+0] += a * w1.x + b * w2.x;
      accs[q*4+1] += a * w1.y + b * w2.y;
      accs[q*4+2] += a * w1.z + b * w2.z;
      accs[q*4+3] += a * w1.w + b * w2.w;
    }
  }
  int node = node0 + r;
  if (node < N_NODES) {
    #pragma unroll
    for (int i = 0; i < 16; i++)
      hstruct[(size_t)node * HID + c0 + i] = accs[i] + bs[c0 + i];
  }
}

// ---------------- fused LSTM (8 steps) + classifier, W in registers ----------------
// 512 threads = 8 waves, 64 nodes/block. Wave w owns gate cols jj in [16w,16w+16)
// for all 4 gates. Row-block passes keep acc at 16 VGPR: peak ~200 regs, no spill.
#define LB 64
__global__ __launch_bounds__(512, 2) void lstm_kernel(
    const float* __restrict__ hist,          // [N][8][128] f32
    const unsigned short* __restrict__ Wt2,  // frag-ordered bf16
    const unsigned short* __restrict__ Wc2,  // frag-ordered bf16
    const float* __restrict__ b_lstm,        // [512]
    const float* __restrict__ hstruct,       // [N][128]
    const float* __restrict__ b_cls,         // [64]
    float* __restrict__ out)                 // [N][64]
{
  __shared__ alignas(16) unsigned short Abuf[2][64 * 256];  // 2 x 32KB, [row][swz(kb)][8]

  const int tid = threadIdx.x;
  const int lane = tid & 63;
  const int w = tid >> 6;
  const int l15 = lane & 15;
  const int l4 = lane >> 4;
  const int base = blockIdx.x * LB;
  const int jj = w * 16 + l15;     // hidden unit owned by this lane

  // persistent B fragments: Bfr[g][kk]  (128 VGPR)
  short8 Bfr[4][8];
  #pragma unroll
  for (int g = 0; g < 4; g++)
    #pragma unroll
    for (int kk = 0; kk < 8; kk++)
      Bfr[g][kk] = *(const short8*)&Wt2[((w * 32 + g * 8 + kk) * 64 + lane) * 8];

  const float bi  = b_lstm[jj];
  const float bf_ = b_lstm[128 + jj];
  const float bg  = b_lstm[256 + jj];
  const float bo  = b_lstm[384 + jj];

  float c_st[16];
  #pragma unroll
  for (int i = 0; i < 16; i++) c_st[i] = 0.f;

  // prologue: zero h-region of buf0, stage x(0) into buf0
  for (int u = tid; u < 64 * 16; u += 512) {
    int row = u >> 4;
    int kbh = u & 15;
    short8 z = {0,0,0,0,0,0,0,0};
    *(short8*)&Abuf[0][row * 256 + 128 + kbh * 8] = z;
  }
  #pragma unroll
  for (int i2 = 0; i2 < 2; i2++) {
    int u = tid + (i2 << 9);
    int row = u >> 4;
    int kb = u & 15;
    int node = base + row;
    float4 x0 = make_float4(0.f,0.f,0.f,0.f), x1 = make_float4(0.f,0.f,0.f,0.f);
    if (node < N_NODES) {
      const float4* p = (const float4*)&hist[(size_t)node * (T_HIST * HID) + kb * 8];
      x0 = p[0]; x1 = p[1];
    }
    short8 v;
    v[0] = (short)f2bf(x0.x); v[1] = (short)f2bf(x0.y);
    v[2] = (short)f2bf(x0.z); v[3] = (short)f2bf(x0.w);
    v[4] = (short)f2bf(x1.x); v[5] = (short)f2bf(x1.y);
    v[6] = (short)f2bf(x1.z); v[7] = (short)f2bf(x1.w);
    int sb = (kb & 8) | ((kb & 7) ^ (row & 7));
    *(short8*)&Abuf[0][row * 256 + sb * 8] = v;
  }
  __syncthreads();

  float4 xp[4];  // prefetch regs (16 VGPR)

  // ---- steps 0..6 ----
  #pragma unroll
  for (int t = 0; t < T_HIST - 1; t++) {
    unsigned short* Acur = &Abuf[t & 1][0];
    unsigned short* Anxt = &Abuf[(t & 1) ^ 1][0];

    // issue x(t+1) global loads early: latency hides under MFMA phase
    #pragma unroll
    for (int i2 = 0; i2 < 2; i2++) {
      int u = tid + (i2 << 9);
      int row = u >> 4;
      int kb = u & 15;
      int node = base + row;
      if (node < N_NODES) {
        const float4* p = (const float4*)&hist[(size_t)node * (T_HIST * HID) + (t + 1) * HID + kb * 8];
        xp[i2 * 2]     = p[0];
        xp[i2 * 2 + 1] = p[1];
      } else {
        xp[i2 * 2]     = make_float4(0.f,0.f,0.f,0.f);
        xp[i2 * 2 + 1] = make_float4(0.f,0.f,0.f,0.f);
      }
    }

    // 4 row-block passes; acc (16 VGPR) dies at end of each pass
    #pragma unroll
    for (int rb = 0; rb < 4; rb++) {
      f32x4 acc[4];
      #pragma unroll
      for (int g = 0; g < 4; g++) { f32x4 z = {0.f,0.f,0.f,0.f}; acc[g] = z; }
      #pragma unroll
      for (int kk = 0; kk < 8; kk++) {
        int row = rb * 16 + l15;
        int kb = kk * 4 + l4;
        int sb = (kb & 24) | ((kb & 7) ^ (row & 7));
        short8 a = *(const short8*)&Acur[row * 256 + sb * 8];
        #pragma unroll
        for (int g = 0; g < 4; g++)
          acc[g] = __builtin_amdgcn_mfma_f32_16x16x32_bf16(a, Bfr[g][kk], acc[g], 0, 0, 0);
      }
      // cell update for this row block; h -> Anxt h-region
      #pragma unroll
      for (int reg = 0; reg < 4; reg++) {
        int r = rb * 4 + reg;
        float gi = sigm(acc[0][reg] + bi);
        float gf = sigm(acc[1][reg] + bf_);
        float gg = tanh_f(acc[2][reg] + bg);
        float go = sigm(acc[3][reg] + bo);
        float c = gf * c_st[r] + gi * gg;
        c_st[r] = c;
        float h = go * tanh_f(c);
        int row = rb * 16 + l4 * 4 + reg;
        int kb = 16 + (jj >> 3);
        int sb = (kb & 24) | ((kb & 7) ^ (row & 7));
        Anxt[row * 256 + sb * 8 + (jj & 7)] = f2bf(h);
      }
      __builtin_amdgcn_sched_barrier(0);  // keep passes separate: acc stays 16 regs
    }

    // write staged x(t+1) into next buffer's x-region
    #pragma unroll
    for (int i2 = 0; i2 < 2; i2++) {
      int u = tid + (i2 << 9);
      int row = u >> 4;
      int kb = u & 15;
      float4 a0 = xp[i2 * 2], a1 = xp[i2 * 2 + 1];
      short8 v;
      v[0] = (short)f2bf(a0.x); v[1] = (short)f2bf(a0.y);
      v[2] = (short)f2bf(a0.z); v[3] = (short)f2bf(a0.w);
      v[4] = (short)f2bf(a1.x); v[5] = (short)f2bf(a1.y);
      v[6] = (short)f2bf(a1.z); v[7] = (short)f2bf(a1.w);
      int sb = (kb & 8) | ((kb & 7) ^ (row & 7));
      *(short8*)&Anxt[row * 256 + sb * 8] = v;
    }
    __syncthreads();   // single barrier per step
  }

  // ---- t = 7 (peeled): final step + classifier epilogue ----
  {
    unsigned short* Acur = &Abuf[1][0];
    unsigned short* Anxt = &Abuf[0][0];

    // pre-issue epilogue loads (overlap with MFMA): hstruct rows + Wc frags
    float hs[16];
    #pragma unroll
    for (int rb = 0; rb < 4; rb++) {
      #pragma unroll
      for (int reg = 0; reg < 4; reg++) {
        int row = rb * 16 + l4 * 4 + reg;
        int node = base + row;
        hs[rb * 4 + reg] = (node < N_NODES) ? hstruct[(size_t)node * HID + jj] : 0.f;
      }
    }
    short8 bc[2][4];
    #pragma unroll
    for (int fi = 0; fi < 2; fi++) {
      int f = w * 2 + fi;
      int cbo = f & 3;
      #pragma unroll
      for (int kk = 0; kk < 4; kk++)
        bc[fi][kk] = *(const short8*)&Wc2[((cbo * 4 + kk) * 64 + lane) * 8];
    }

    #pragma unroll
    for (int rb = 0; rb < 4; rb++) {
      f32x4 acc[4];
      #pragma unroll
      for (int g = 0; g < 4; g++) { f32x4 z = {0.f,0.f,0.f,0.f}; acc[g] = z; }
      #pragma unroll
      for (int kk = 0; kk < 8; kk++) {
        int row = rb * 16 + l15;
        int kb = kk * 4 + l4;
        int sb = (kb & 24) | ((kb & 7) ^ (row & 7));
        short8 a = *(const short8*)&Acur[row * 256 + sb * 8];
        #pragma unroll
        for (int g = 0; g < 4; g++)
          acc[g] = __builtin_amdgcn_mfma_f32_16x16x32_bf16(a, Bfr[g][kk], acc[g], 0, 0, 0);
      }
      #pragma unroll
      for (int reg = 0; reg < 4; reg++) {
        int r = rb * 4 + reg;
        float gi = sigm(acc[0][reg] + bi);
        float gf = sigm(acc[1][reg] + bf_);
        float gg = tanh_f(acc[2][reg] + bg);
        float go = sigm(acc[3][reg] + bo);
        float c = gf * c_st[r] + gi * gg;
        float h = go * tanh_f(c);
        float comb = hs[r] + h;
        int row = rb * 16 + l4 * 4 + reg;
        int kb = jj >> 3;
        int sb = (kb & 8) | ((kb & 7) ^ (row & 7));
        Anxt[row * 256 + sb * 8 + (jj & 7)] = f2bf(comb);
      }
      __builtin_amdgcn_sched_barrier(0);
    }
    __syncthreads();

    // classifier: out = comb @ W_cls + b_cls
    #pragma unroll
    for (int fi = 0; fi < 2; fi++) {
      int f = w * 2 + fi;
      int rbo = f >> 2, cbo = f & 3;
      f32x4 o = {0.f,0.f,0.f,0.f};
      #pragma unroll
      for (int kk = 0; kk < 4; kk++) {
        int row = rbo * 16 + l15;
        int kb = kk * 4 + l4;
        int sb = (kb & 8) | ((kb & 7) ^ (row & 7));
        short8 a = *(const short8*)&Anxt[row * 256 + sb * 8];
        o = __builtin_amdgcn_mfma_f32_16x16x32_bf16(a, bc[fi][kk], o, 0, 0, 0);
      }
      int col = cbo * 16 + l15;
      float bcl = b_cls[col];
      #pragma unroll
      for (int reg = 0; reg < 4; reg++) {
        int row = rbo * 16 + l4 * 4 + reg;
        int node = base + row;
        if (node < N_NODES) out[(size_t)node * OUT_DIM + col] = o[reg] + bcl;
      }
    }
  }
}

// ---------------- launch ----------------
extern "C" void kernel_launch(void* const* d_in, const int* in_sizes, int n_in,
                              void* d_out, int out_size, void* d_ws, size_t ws_size,
                              hipStream_t stream) {
  (void)in_sizes; (void)n_in; (void)out_size; (void)ws_size;
  const float* node_feats = (const float*)d_in[0];
  const float* hist       = (const float*)d_in[1];
  const int*   src        = (const int*)d_in[2];
  const int*   dst        = (const int*)d_in[3];
  const float* W_self     = (const float*)d_in[4];
  const float* W_neigh    = (const float*)d_in[5];
  const float* b_sage     = (const float*)d_in[6];
  const float* w_ih       = (const float*)d_in[7];
  const float* w_hh       = (const float*)d_in[8];
  const float* b_lstm     = (const float*)d_in[9];
  const float* W_cls      = (const float*)d_in[10];
  const float* b_cls      = (const float*)d_in[11];
  float* out = (float*)d_out;

  char* ws = (char*)d_ws;
  int* cnt        = (int*)(ws);                    // 200,000 -> pad 200,192
  int* lexcl      = (int*)(ws + 200192);           // 200,000 -> 400,384
  int* rowstart   = (int*)(ws + 400384);           // 200,000 -> 600,576
  int* cursor     = (int*)(ws + 600576);           // 200,000 -> 800,768
  int* btot       = (int*)(ws + 800768);           // 256
  int* bbase      = (int*)(ws + 801024);           // 256
  int* esrc       = (int*)(ws + 801280);           // 3,200,000 -> 4,001,280
  float* hstruct  = (float*)(ws + 4001280);        // 25,600,000 -> 29,601,280
  unsigned short* Wt2 = (unsigned short*)(ws + 29601280);  // 262,144
  unsigned short* Wc2 = (unsigned short*)(ws + 29863424);  // 16,384

  hipMemsetAsync(cnt, 0, 200000, stream);
  prepack_kernel<<<64, 256, 0, stream>>>(w_ih, w_hh, W_cls, Wt2, Wc2);
  count_kernel<<<(N_EDGES + 255) / 256, 256, 0, stream>>>(dst, cnt);
  scan1_kernel<<<NB_SCAN, 256, 0, stream>>>(cnt, lexcl, btot);
  scan2_kernel<<<1, 64, 0, stream>>>(btot, bbase);
  scan3_kernel<<<(N_NODES + 255) / 256, 256, 0, stream>>>(lexcl, bbase, rowstart, cursor);
  fill_kernel<<<(N_EDGES + 255) / 256, 256, 0, stream>>>(src, dst, cursor, esrc);
  hstruct_kernel<<<(N_NODES + HS_TILE - 1) / HS_TILE, 256, 0, stream>>>(
      node_feats, esrc, rowstart, cnt, W_self, W_neigh, b_sage, hstruct);
  lstm_kernel<<<(N_NODES + LB - 1) / LB, 512, 0, stream>>>(
      hist, Wt2, Wc2, b_lstm, hstruct, b_cls, out);
}